// Round 5
// baseline (8579.267 us; speedup 1.0000x reference)
//
#include <hip/hip_runtime.h>

// Problem constants (fixed by the reference)
#define M_ROWS 106496   // 4096*26  (n,v) rows = 416*256
#define NBATCH 4096
#define VN 26
#define KNUM 3
#define TS 25

typedef unsigned short u16;
typedef __attribute__((ext_vector_type(8))) short v8s;
typedef __attribute__((ext_vector_type(4))) float v4f;

#define MFMA(a, b, c) __builtin_amdgcn_mfma_f32_16x16x32_bf16(a, b, c, 0, 0, 0)

__device__ __forceinline__ u16 f2bf(float f) {
    unsigned u = __float_as_uint(f);
    u += 0x7FFF + ((u >> 16) & 1);   // RNE
    return (u16)(u >> 16);
}
__device__ __forceinline__ float bf2f(u16 h) {
    return __uint_as_float(((unsigned)h) << 16);
}
__device__ __forceinline__ float sigm(float x) {
    return 1.f / (1.f + __expf(-x));
}
__device__ __forceinline__ float tanh_fast(float x) {
    return 2.f / (1.f + __expf(-2.f * x)) - 1.f;
}

// Async global->LDS, 16B/lane. LDS dest = wave-uniform base (HW adds lane*16);
// global source address may vary per lane (verified m104).
typedef const __attribute__((address_space(1))) unsigned int* gas_t;
typedef __attribute__((address_space(3))) unsigned int* las_t;
__device__ __forceinline__ void gl16(const void* g, void* l) {
    __builtin_amdgcn_global_load_lds((gas_t)g, (las_t)l, 16, 0, 0);
}

// ---------------------------------------------------------------------------
// GRU v5: 512 thr (8 waves: 4 row-groups x 2 col-groups), BM=256, BN=64,
// K=288. Phases of BK=64 staged via global_load_lds into seg-major LDS
// (Al[seg][256 rows]*16B, Bl[seg][192 rows]*16B): wave-uniform LDS bases and
// 2-way-free bank pattern on ds_read_b128. Final K=32 (xpad + x-weights)
// peeled, read per-lane from L2. Grid (416, 4).
// ---------------------------------------------------------------------------
__global__ __launch_bounds__(512, 2) void gru_v5(
    const u16* __restrict__ Am, const u16* __restrict__ xpad,
    const u16* __restrict__ hprev, u16* __restrict__ hout,
    const u16* __restrict__ wfull, const u16* __restrict__ wxn)
{
    __shared__ u16 Al[8 * 256 * 8];   // 32 KB: [seg][row] * 16B
    __shared__ u16 Bl[8 * 192 * 8];   // 24 KB: [seg][row] * 16B
    const int m0 = blockIdx.x * 256;
    const int n0 = blockIdx.y * 64;
    const int tid = threadIdx.x, wid = tid >> 6, lane = tid & 63;
    const int ln = lane & 15, q = lane >> 4;
    const int rg = wid >> 1;              // 0..3 -> 64-row group
    const int wn = (wid & 1) * 32;        // 0/32 col group

    v4f accr[4][2] = {}, accz[4][2] = {}, acch[4][2] = {}, accn[4][2] = {};

    for (int p = 0; p < 4; ++p) {
        // stage A: 8 segs x 256 rows; issue u = t*8+wid -> s=2t+(wid>>2), rg4=wid&3
#pragma unroll
        for (int t = 0; t < 4; ++t) {
            int u = t * 8 + wid;
            int s = u >> 2, rg4 = u & 3;
            int row = rg4 * 64 + lane;
            gl16(&Am[(size_t)(m0 + row) * 256 + p * 64 + s * 8],
                 &Al[(s * 256 + rg4 * 64) * 8]);
        }
        // stage B: 8 segs x 192 rows (3 gates x 64 cols of n0-slice)
#pragma unroll
        for (int t = 0; t < 3; ++t) {
            int u = t * 8 + wid;
            int s = u & 7, rg3 = u >> 3;
            int row = rg3 * 64 + lane;
            int wrow = (row >> 6) * 256 + n0 + (row & 63);
            gl16(&wfull[(size_t)wrow * 288 + p * 64 + s * 8],
                 &Bl[(s * 192 + rg3 * 64) * 8]);
        }
        __syncthreads();
#pragma unroll
        for (int kt2 = 0; kt2 < 2; ++kt2) {
            v8s af[4], br[2], bz[2], bh[2];
            const int sb = kt2 * 4 + q;
#pragma unroll
            for (int i = 0; i < 4; ++i) {
                int row = rg * 64 + i * 16 + ln;
                af[i] = *(const v8s*)&Al[(sb * 256 + row) * 8];
            }
#pragma unroll
            for (int j = 0; j < 2; ++j) {
                int rl = wn + j * 16 + ln;
                br[j] = *(const v8s*)&Bl[(sb * 192 + rl) * 8];
                bz[j] = *(const v8s*)&Bl[(sb * 192 + 64 + rl) * 8];
                bh[j] = *(const v8s*)&Bl[(sb * 192 + 128 + rl) * 8];
            }
#pragma unroll
            for (int i = 0; i < 4; ++i)
#pragma unroll
                for (int j = 0; j < 2; ++j) {
                    accr[i][j] = MFMA(af[i], br[j], accr[i][j]);
                    accz[i][j] = MFMA(af[i], bz[j], accz[i][j]);
                    acch[i][j] = MFMA(af[i], bh[j], acch[i][j]);
                }
        }
        __syncthreads();
    }

    // peeled final K=32: A = xpad, B = wfull cols 256..287, + wxn (n-gate x)
    {
        v8s af[4], br[2], bz[2], bh[2], bn[2];
#pragma unroll
        for (int i = 0; i < 4; ++i)
            af[i] = *(const v8s*)&xpad[(size_t)(m0 + rg * 64 + i * 16 + ln) * 32 + q * 8];
#pragma unroll
        for (int j = 0; j < 2; ++j) {
            int rl = n0 + wn + j * 16 + ln;
            br[j] = *(const v8s*)&wfull[(size_t)rl * 288 + 256 + q * 8];
            bz[j] = *(const v8s*)&wfull[(size_t)(256 + rl) * 288 + 256 + q * 8];
            bh[j] = *(const v8s*)&wfull[(size_t)(512 + rl) * 288 + 256 + q * 8];
            bn[j] = *(const v8s*)&wxn[(size_t)(n0 + wn + j * 16 + ln) * 32 + q * 8];
        }
#pragma unroll
        for (int i = 0; i < 4; ++i)
#pragma unroll
            for (int j = 0; j < 2; ++j) {
                accr[i][j] = MFMA(af[i], br[j], accr[i][j]);
                accz[i][j] = MFMA(af[i], bz[j], accz[i][j]);
                acch[i][j] = MFMA(af[i], bh[j], acch[i][j]);
                accn[i][j] = MFMA(af[i], bn[j], accn[i][j]);
            }
    }

#pragma unroll
    for (int i = 0; i < 4; ++i)
#pragma unroll
        for (int j = 0; j < 2; ++j) {
            int gc = n0 + wn + j * 16 + ln;
#pragma unroll
            for (int r = 0; r < 4; ++r) {
                int gr = m0 + rg * 64 + i * 16 + q * 4 + r;
                float rgg = sigm(accr[i][j][r]);
                float zg = sigm(accz[i][j][r]);
                float nn = tanh_fast(accn[i][j][r] + rgg * acch[i][j][r]);
                float hp = bf2f(hprev[(size_t)gr * 256 + gc]);
                hout[(size_t)gr * 256 + gc] = f2bf((1.f - zg) * nn + zg * hp);
            }
        }
}

// ---------------------------------------------------------------------------
// Conv gemm v5: 512 thr (4x2 waves, wave 64r x 64c), BM=256, BN=128, K=256
// in 4 phases of BK=64. Same seg-major staging. Grid (416, 6).
// ---------------------------------------------------------------------------
__global__ __launch_bounds__(512, 2) void conv_v5(
    const u16* __restrict__ A, const u16* __restrict__ convw,
    const float* __restrict__ convb, u16* __restrict__ y)
{
    __shared__ u16 Al[8 * 256 * 8];   // 32 KB
    __shared__ u16 Bl[8 * 128 * 8];   // 16 KB
    const int m0 = blockIdx.x * 256;
    const int n0 = blockIdx.y * 128;
    const int tid = threadIdx.x, wid = tid >> 6, lane = tid & 63;
    const int ln = lane & 15, q = lane >> 4;
    const int rg = wid >> 1;
    const int wn = (wid & 1) * 64;

    v4f acc[4][4] = {};
    for (int p = 0; p < 4; ++p) {
#pragma unroll
        for (int t = 0; t < 4; ++t) {
            int u = t * 8 + wid;
            int s = u >> 2, rg4 = u & 3;
            int row = rg4 * 64 + lane;
            gl16(&A[(size_t)(m0 + row) * 256 + p * 64 + s * 8],
                 &Al[(s * 256 + rg4 * 64) * 8]);
        }
#pragma unroll
        for (int t = 0; t < 2; ++t) {
            int u = t * 8 + wid;
            int s = u & 7, rg2 = u >> 3;
            int row = rg2 * 64 + lane;
            gl16(&convw[(size_t)(n0 + row) * 256 + p * 64 + s * 8],
                 &Bl[(s * 128 + rg2 * 64) * 8]);
        }
        __syncthreads();
#pragma unroll
        for (int kt2 = 0; kt2 < 2; ++kt2) {
            const int sb = kt2 * 4 + q;
            v8s af[4], bf_[4];
#pragma unroll
            for (int i = 0; i < 4; ++i)
                af[i] = *(const v8s*)&Al[(sb * 256 + rg * 64 + i * 16 + ln) * 8];
#pragma unroll
            for (int j = 0; j < 4; ++j)
                bf_[j] = *(const v8s*)&Bl[(sb * 128 + wn + j * 16 + ln) * 8];
#pragma unroll
            for (int i = 0; i < 4; ++i)
#pragma unroll
                for (int j = 0; j < 4; ++j)
                    acc[i][j] = MFMA(af[i], bf_[j], acc[i][j]);
        }
        __syncthreads();
    }
#pragma unroll
    for (int i = 0; i < 4; ++i)
#pragma unroll
        for (int j = 0; j < 4; ++j) {
            int gc = n0 + wn + j * 16 + ln;
            float b = convb[gc];
#pragma unroll
            for (int r = 0; r < 4; ++r) {
                int gr = m0 + rg * 64 + i * 16 + q * 4 + r;
                y[(size_t)gr * 768 + gc] = f2bf(acc[i][j][r] + b);
            }
        }
}

// ---------------------------------------------------------------------------
// Graph mix: msg[(n,w),c] = sum_{k,v} y[(n,v),k*256+c] * aadj[k][v][w]
// ---------------------------------------------------------------------------
__global__ __launch_bounds__(256) void graph_mix(
    const u16* __restrict__ y, const float* __restrict__ aadj,
    u16* __restrict__ msg)
{
    __shared__ u16 yl[VN * 768];
    const int n = blockIdx.x, tid = threadIdx.x;
    const uint4* src = (const uint4*)(y + (size_t)n * VN * 768);
    for (int idx = tid; idx < VN * 768 / 8; idx += 256)
        ((uint4*)yl)[idx] = src[idx];
    __syncthreads();
    const int c = tid;
    float acc[VN] = {};
    for (int k = 0; k < KNUM; ++k)
        for (int v = 0; v < VN; ++v) {
            float yv = bf2f(yl[v * 768 + k * 256 + c]);
            const float* ap = &aadj[(k * VN + v) * VN];
#pragma unroll
            for (int w = 0; w < VN; ++w) acc[w] += yv * ap[w];
        }
    size_t base = (size_t)n * VN * 256;
    for (int w = 0; w < VN; ++w) msg[base + w * 256 + c] = f2bf(acc[w]);
}

// ---------------------------------------------------------------------------
// Fused MLP + head (R3-validated): hd=lrelu(h@W1^T+b1); hd2=lrelu(hd@W2^T+b2);
// res=hd2@W3^T+b3; pred=P1+res -> out[:,s], pnew, next xpad.
// ---------------------------------------------------------------------------
__global__ __launch_bounds__(256) void mlp_head(
    const u16* __restrict__ h, const u16* __restrict__ w1,
    const float* __restrict__ b1, const u16* __restrict__ w2,
    const float* __restrict__ b2, const float* __restrict__ w3,
    const float* __restrict__ b3, const float* __restrict__ p1,
    const float* __restrict__ p2, float* __restrict__ pnew,
    u16* __restrict__ xpad, float* __restrict__ out, int s)
{
    __shared__ u16 hdl[64 * 264];
    __shared__ float w3l[768];
    const int tid = threadIdx.x, wid = tid >> 6, lane = tid & 63;
    const int ln = lane & 15, q = lane >> 4;
    const int r0 = blockIdx.x * 64;
    for (int idx = tid; idx < 768; idx += 256) w3l[idx] = w3[idx];

    {
        v4f acc[4][4] = {};
#pragma unroll
        for (int kt = 0; kt < 8; ++kt) {
            v8s af[4], bf_[4];
#pragma unroll
            for (int i = 0; i < 4; ++i)
                af[i] = *(const v8s*)&h[(size_t)(r0 + i * 16 + ln) * 256 + kt * 32 + q * 8];
#pragma unroll
            for (int j = 0; j < 4; ++j)
                bf_[j] = *(const v8s*)&w1[(size_t)(wid * 64 + j * 16 + ln) * 256 + kt * 32 + q * 8];
#pragma unroll
            for (int i = 0; i < 4; ++i)
#pragma unroll
                for (int j = 0; j < 4; ++j)
                    acc[i][j] = MFMA(af[i], bf_[j], acc[i][j]);
        }
#pragma unroll
        for (int i = 0; i < 4; ++i)
#pragma unroll
            for (int j = 0; j < 4; ++j) {
                int col = wid * 64 + j * 16 + ln;
                float bb = b1[col];
#pragma unroll
                for (int r = 0; r < 4; ++r) {
                    float v = acc[i][j][r] + bb;
                    v = v > 0.f ? v : 0.1f * v;
                    hdl[(i * 16 + q * 4 + r) * 264 + col] = f2bf(v);
                }
            }
    }
    __syncthreads();

    v4f acc2[4][4] = {};
#pragma unroll
    for (int kt = 0; kt < 8; ++kt) {
        v8s af[4], bf_[4];
#pragma unroll
        for (int i = 0; i < 4; ++i)
            af[i] = *(const v8s*)&hdl[(i * 16 + ln) * 264 + kt * 32 + q * 8];
#pragma unroll
        for (int j = 0; j < 4; ++j)
            bf_[j] = *(const v8s*)&w2[(size_t)(wid * 64 + j * 16 + ln) * 256 + kt * 32 + q * 8];
#pragma unroll
        for (int i = 0; i < 4; ++i)
#pragma unroll
            for (int j = 0; j < 4; ++j)
                acc2[i][j] = MFMA(af[i], bf_[j], acc2[i][j]);
    }
    __syncthreads();
#pragma unroll
    for (int i = 0; i < 4; ++i)
#pragma unroll
        for (int j = 0; j < 4; ++j) {
            int col = wid * 64 + j * 16 + ln;
            float bb = b2[col];
#pragma unroll
            for (int r = 0; r < 4; ++r) {
                float v = acc2[i][j][r] + bb;
                v = v > 0.f ? v : 0.1f * v;
                hdl[(i * 16 + q * 4 + r) * 264 + col] = f2bf(v);
            }
        }
    __syncthreads();

    const int row = tid >> 2, seg = tid & 3;
    float s0 = 0.f, s1 = 0.f, s2 = 0.f;
#pragma unroll
    for (int t8 = 0; t8 < 8; ++t8) {
        v8s hv = *(const v8s*)&hdl[row * 264 + seg * 64 + t8 * 8];
#pragma unroll
        for (int e = 0; e < 8; ++e) {
            float f = bf2f((u16)hv[e]);
            int c = seg * 64 + t8 * 8 + e;
            s0 += f * w3l[c];
            s1 += f * w3l[256 + c];
            s2 += f * w3l[512 + c];
        }
    }
    s0 += __shfl_xor(s0, 1); s0 += __shfl_xor(s0, 2);
    s1 += __shfl_xor(s1, 1); s1 += __shfl_xor(s1, 2);
    s2 += __shfl_xor(s2, 1); s2 += __shfl_xor(s2, 2);
    if (seg == 0) {
        const int gm = r0 + row;
        float a0 = p1[gm * 3 + 0], a1 = p1[gm * 3 + 1], a2 = p1[gm * 3 + 2];
        float c0 = p2[gm * 3 + 0], c1 = p2[gm * 3 + 1], c2 = p2[gm * 3 + 2];
        float o0 = a0 + s0 + b3[0];
        float o1 = a1 + s1 + b3[1];
        float o2 = a2 + s2 + b3[2];
        size_t ob = ((size_t)gm * TS + s) * 3;
        out[ob + 0] = o0; out[ob + 1] = o1; out[ob + 2] = o2;
        pnew[gm * 3 + 0] = o0; pnew[gm * 3 + 1] = o1; pnew[gm * 3 + 2] = o2;
        u16 xs[32];
#pragma unroll
        for (int e = 0; e < 32; ++e) xs[e] = 0;
        xs[0] = f2bf(o0); xs[1] = f2bf(o1); xs[2] = f2bf(o2);
        xs[3] = f2bf(a0 - c0); xs[4] = f2bf(a1 - c1); xs[5] = f2bf(a2 - c2);
        xs[6] = f2bf(o0 - 2.f * a0 + c0);
        xs[7] = f2bf(o1 - 2.f * a1 + c1);
        xs[8] = f2bf(o2 - 2.f * a2 + c2);
        xs[9] = f2bf(1.f);
        uint4* xd = (uint4*)&xpad[(size_t)gm * 32];
#pragma unroll
        for (int t = 0; t < 4; ++t) {
            uint4 u;
            u.x = (unsigned)xs[t * 8 + 0] | ((unsigned)xs[t * 8 + 1] << 16);
            u.y = (unsigned)xs[t * 8 + 2] | ((unsigned)xs[t * 8 + 3] << 16);
            u.z = (unsigned)xs[t * 8 + 4] | ((unsigned)xs[t * 8 + 5] << 16);
            u.w = (unsigned)xs[t * 8 + 6] | ((unsigned)xs[t * 8 + 7] << 16);
            xd[t] = u;
        }
    }
}

// ---------------------------------------------------------------------------
// Step-0 xpad from the three input frames.
// ---------------------------------------------------------------------------
__global__ __launch_bounds__(256) void init_xpad(
    const float* __restrict__ x0, const float* __restrict__ xp,
    const float* __restrict__ xp2, u16* __restrict__ xpad)
{
    int m = blockIdx.x * 256 + threadIdx.x;
    float a0 = x0[m * 3 + 0], a1 = x0[m * 3 + 1], a2 = x0[m * 3 + 2];
    float b0 = xp[m * 3 + 0], b1 = xp[m * 3 + 1], b2 = xp[m * 3 + 2];
    float c0 = xp2[m * 3 + 0], c1 = xp2[m * 3 + 1], c2 = xp2[m * 3 + 2];
    unsigned t[32];
#pragma unroll
    for (int i = 0; i < 32; ++i) t[i] = 0;
    t[0] = f2bf(a0); t[1] = f2bf(a1); t[2] = f2bf(a2);
    t[3] = f2bf(b0 - c0); t[4] = f2bf(b1 - c1); t[5] = f2bf(b2 - c2);
    t[6] = f2bf(a0 - 2.f * b0 + c0);
    t[7] = f2bf(a1 - 2.f * b1 + c1);
    t[8] = f2bf(a2 - 2.f * b2 + c2);
    t[9] = f2bf(1.f);
    uint4* dst = (uint4*)&xpad[(size_t)m * 32];
#pragma unroll
    for (int wq = 0; wq < 4; ++wq) {
        uint4 u;
        u.x = t[wq * 8 + 0] | (t[wq * 8 + 1] << 16);
        u.y = t[wq * 8 + 2] | (t[wq * 8 + 3] << 16);
        u.z = t[wq * 8 + 4] | (t[wq * 8 + 5] << 16);
        u.w = t[wq * 8 + 6] | (t[wq * 8 + 7] << 16);
        dst[wq] = u;
    }
}

// ---------------------------------------------------------------------------
// hidden [N,C,V] fp32 -> h[(n,v),c] bf16.
// ---------------------------------------------------------------------------
__global__ __launch_bounds__(256) void transpose_h(
    const float* __restrict__ hidden, u16* __restrict__ hA)
{
    __shared__ float hl[256 * VN];
    const int n = blockIdx.x, tid = threadIdx.x;
    const uint4* src = (const uint4*)(hidden + (size_t)n * 256 * VN);
    for (int idx = tid; idx < 256 * VN / 4; idx += 256)
        ((uint4*)hl)[idx] = src[idx];
    __syncthreads();
    size_t base = (size_t)n * VN * 256;
    for (int idx = tid; idx < VN * 256; idx += 256) {
        int v = idx >> 8, c = idx & 255;
        hA[base + idx] = f2bf(hl[c * VN + v]);
    }
}

// ---------------------------------------------------------------------------
// Weight packing (once per call): wfull288, wxn, w1, w2, convw, aadj.
// ---------------------------------------------------------------------------
__global__ __launch_bounds__(256) void pack_weights(
    const float* __restrict__ Whr, const float* __restrict__ Whi,
    const float* __restrict__ Whh, const float* __restrict__ W1f,
    const float* __restrict__ W2f, const float* __restrict__ convw_f,
    const float* __restrict__ Af, const float* __restrict__ emul,
    const float* __restrict__ eadd, const float* __restrict__ Wir,
    const float* __restrict__ Wii, const float* __restrict__ Win,
    const float* __restrict__ bir, const float* __restrict__ bii,
    const float* __restrict__ b_in,
    u16* __restrict__ wfull, u16* __restrict__ wxn, u16* __restrict__ w1,
    u16* __restrict__ w2, u16* __restrict__ convw, float* __restrict__ aadj)
{
    int gid = blockIdx.x * 256 + threadIdx.x;
    int stride = gridDim.x * 256;
    for (int i = gid; i < 768 * 288; i += stride) {
        int row = i / 288, col = i - row * 288;
        int g = row >> 8, c = row & 255;
        float v = 0.f;
        if (col < 256)
            v = (g == 0 ? Whr : (g == 1 ? Whi : Whh))[c * 256 + col];
        else if (col < 265) {
            int tcol = col - 256;
            v = (g == 0 ? Wir[c * 9 + tcol] : (g == 1 ? Wii[c * 9 + tcol] : 0.f));
        } else if (col == 265)
            v = (g == 0 ? bir[c] : (g == 1 ? bii[c] : 0.f));
        wfull[i] = f2bf(v);
    }
    for (int i = gid; i < 256 * 32; i += stride) {
        int c = i >> 5, col = i & 31;
        float v = 0.f;
        if (col < 9) v = Win[c * 9 + col];
        else if (col == 9) v = b_in[c];
        wxn[i] = f2bf(v);
    }
    for (int i = gid; i < 65536; i += stride) {
        w1[i] = f2bf(W1f[i]);
        w2[i] = f2bf(W2f[i]);
    }
    for (int i = gid; i < 196608; i += stride) convw[i] = f2bf(convw_f[i]);
    for (int i = gid; i < KNUM * VN * VN; i += stride)
        aadj[i] = Af[i] * emul[i] + eadd[i];
}

// ---------------------------------------------------------------------------
extern "C" void kernel_launch(void* const* d_in, const int* in_sizes, int n_in,
                              void* d_out, int out_size, void* d_ws, size_t ws_size,
                              hipStream_t stream)
{
    const float* inputs   = (const float*)d_in[0];
    const float* inputs_p = (const float*)d_in[1];
    const float* inputs_p2= (const float*)d_in[2];
    const float* hidden   = (const float*)d_in[3];
    const float* Af       = (const float*)d_in[4];
    const float* emul     = (const float*)d_in[5];
    const float* eadd     = (const float*)d_in[6];
    const float* conv_w   = (const float*)d_in[7];
    const float* conv_b   = (const float*)d_in[8];
    const float* Wir      = (const float*)d_in[9];
    const float* bir      = (const float*)d_in[10];
    const float* Wii      = (const float*)d_in[11];
    const float* bii      = (const float*)d_in[12];
    const float* Win      = (const float*)d_in[13];
    const float* b_in     = (const float*)d_in[14];
    const float* Whr      = (const float*)d_in[15];
    const float* Whi      = (const float*)d_in[16];
    const float* Whh      = (const float*)d_in[17];
    const float* W1f      = (const float*)d_in[18];
    const float* b1f      = (const float*)d_in[19];
    const float* W2f      = (const float*)d_in[20];
    const float* b2f      = (const float*)d_in[21];
    const float* W3f      = (const float*)d_in[22];
    const float* b3f      = (const float*)d_in[23];
    float* out = (float*)d_out;

    const size_t M = M_ROWS;
    char* ws = (char*)d_ws;
    size_t off = 0;
    auto alloc = [&](size_t bytes) -> void* {
        void* p = ws + off;
        off = (off + bytes + 255) & ~(size_t)255;
        return p;
    };
    u16* ybuf  = (u16*)alloc(M * 768 * 2);
    u16* msg   = (u16*)alloc(M * 256 * 2);
    u16* hA    = (u16*)alloc(M * 256 * 2);
    u16* hB    = (u16*)alloc(M * 256 * 2);
    u16* xpad  = (u16*)alloc(M * 32 * 2);
    float* pa  = (float*)alloc(M * 3 * 4);
    float* pb  = (float*)alloc(M * 3 * 4);
    float* pc  = (float*)alloc(M * 3 * 4);
    u16* wfull = (u16*)alloc(768 * 288 * 2);
    u16* wxn   = (u16*)alloc(256 * 32 * 2);
    u16* w1    = (u16*)alloc(65536 * 2);
    u16* w2    = (u16*)alloc(65536 * 2);
    u16* convw = (u16*)alloc(196608 * 2);
    float* aadj = (float*)alloc(KNUM * VN * VN * 4);
    if (off > ws_size) return;

    pack_weights<<<512, 256, 0, stream>>>(
        Whr, Whi, Whh, W1f, W2f, conv_w, Af, emul, eadd, Wir, Wii, Win,
        bir, bii, b_in, wfull, wxn, w1, w2, convw, aadj);
    transpose_h<<<NBATCH, 256, 0, stream>>>(hidden, hA);
    init_xpad<<<M_ROWS / 256, 256, 0, stream>>>(inputs, inputs_p, inputs_p2, xpad);
    hipMemcpyAsync(pa, inputs,    M * 3 * 4, hipMemcpyDeviceToDevice, stream);
    hipMemcpyAsync(pb, inputs_p,  M * 3 * 4, hipMemcpyDeviceToDevice, stream);
    hipMemcpyAsync(pc, inputs_p2, M * 3 * 4, hipMemcpyDeviceToDevice, stream);

    u16* hcur = hA;  u16* hnext = hB;
    float* P1 = pa;  float* P2 = pb;  float* P3 = pc;

    for (int s = 0; s < TS; ++s) {
        const u16* m_ptr;
        if (s < 10) {
            conv_v5<<<dim3(416, 6), 512, 0, stream>>>(hcur, convw, conv_b, ybuf);
            graph_mix<<<NBATCH, 256, 0, stream>>>(ybuf, aadj, msg);
            m_ptr = msg;
        } else {
            m_ptr = hcur;
        }
        gru_v5<<<dim3(416, 4), 512, 0, stream>>>(m_ptr, xpad, hcur, hnext,
                                                 wfull, wxn);
        mlp_head<<<M_ROWS / 64, 256, 0, stream>>>(
            hnext, w1, b1f, w2, b2f, W3f, b3f, P1, P2, P3, xpad, out, s);
        float* t = P3; P3 = P2; P2 = P1; P1 = t;
        u16* ht = hcur; hcur = hnext; hnext = ht;
    }
}